// Round 7
// baseline (169.493 us; speedup 1.0000x reference)
//
#include <hip/hip_runtime.h>

#define EDIM   4096
#define NHEAD  32
#define DHEAD  128
#define LCACHE 8191
#define LTOT   8192
#define NSPLIT 1024
#define RPB    8     // rows per split over rows 0..8191 (last split: 7 valid)
#define NGRP   8     // combine stage-1 groups
#define SPG    128   // splits per group (NSPLIT/NGRP)

#define SCALE 0.08838834764831845f  // 1/sqrt(128)

typedef float __attribute__((ext_vector_type(4))) f32x4;

__device__ __forceinline__ f32x4 ntload4(const float* p) {
    return __builtin_nontemporal_load((const f32x4*)p);
}
__device__ __forceinline__ void ntstore4(float* p, f32x4 v) {
    __builtin_nontemporal_store(v, (f32x4*)p);
}
__device__ __forceinline__ f32x4 ld4(const float* p) {
    return *(const f32x4*)p;
}

// ---------------------------------------------------------------------------
// Kernel 1: q GEMV only (Wq kept temporal for proj reuse).
// One wave per row, 4 rows/block, grid 1024.
// ---------------------------------------------------------------------------
__global__ __launch_bounds__(256) void qgemv_kernel(
    const float* __restrict__ seq,
    const float* __restrict__ Wq, const float* __restrict__ bq,
    float* __restrict__ q_f)
{
    int row  = blockIdx.x * 4 + (threadIdx.x >> 6);
    int lane = threadIdx.x & 63;
    const float* wr = Wq + (size_t)row * EDIM;

    float sum = 0.f;
#pragma unroll
    for (int i = 0; i < 16; ++i) {
        int c = (i * 64 + lane) * 4;
        f32x4 w = ld4(wr + c);
        f32x4 s = ld4(seq + c);
        sum += w.x * s.x + w.y * s.y + w.z * s.z + w.w * s.w;
    }
#pragma unroll
    for (int m = 32; m; m >>= 1) sum += __shfl_xor(sum, m);
    if (lane == 0) q_f[row] = sum + bq[row];
}

// ---------------------------------------------------------------------------
// Kernel 2: MEGA. Blocks [0,NSPLIT): fused KV-copy + flash-decode over
// cached rows only (0..8190), one-pass online softmax, no barriers.
// Blocks [NSPLIT, NSPLIT+2048): k/v-row GEMVs (8192 rows, 4/block),
// overlapping the Wk/Wv weight stream with the KV copy stream.
// ---------------------------------------------------------------------------
__global__ __launch_bounds__(256) void mega_kernel(
    const float* __restrict__ kc, const float* __restrict__ vc,
    const float* __restrict__ q_f, const float* __restrict__ seq,
    const float* __restrict__ Wk, const float* __restrict__ bk,
    const float* __restrict__ Wv, const float* __restrict__ bv,
    float* __restrict__ out,
    float* __restrict__ pm, float* __restrict__ pl, float* __restrict__ po)
{
    int t = threadIdx.x;
    float* knew = out + EDIM;
    float* vnew = out + (size_t)EDIM * (1 + LTOT);

    if (blockIdx.x >= NSPLIT) {
        // ---- GEMV path: k/v projection rows ----
        int idx  = (blockIdx.x - NSPLIT) * 4 + (t >> 6);
        int lane = t & 63;
        int sel  = idx >> 12;          // 0 = k, 1 = v
        int row  = idx & 4095;
        const float* W = sel == 0 ? Wk : Wv;
        const float* b = sel == 0 ? bk : bv;
        const float* wr = W + (size_t)row * EDIM;

        float sum = 0.f;
#pragma unroll
        for (int i = 0; i < 16; ++i) {
            int c = (i * 64 + lane) * 4;
            f32x4 w = ntload4(wr + c);
            f32x4 s = ld4(seq + c);
            sum += w.x * s.x + w.y * s.y + w.z * s.z + w.w * s.w;
        }
#pragma unroll
        for (int m = 32; m; m >>= 1) sum += __shfl_xor(sum, m);
        if (lane == 0) {
            float total = sum + b[row];
            if (sel == 0) out[(size_t)EDIM * (1 + LCACHE) + row] = total;
            else          out[(size_t)EDIM * (1 + LTOT + LCACHE) + row] = total;
        }
        return;
    }

    // ---- attention path: split s over cached rows ----
    int s  = blockIdx.x;
    int g  = t >> 5;                 // head sub-group 0..7
    int r0 = s * RPB;
    int nr = (s == NSPLIT - 1) ? (RPB - 1) : RPB;   // last split: rows 8184..8190
    int c0 = t * 4;                  // chunk j at c0 + j*1024

    float qr[16];
#pragma unroll
    for (int j = 0; j < 4; ++j) {
        f32x4 v = ld4(q_f + j * 1024 + c0);
        qr[j*4+0] = v.x * SCALE; qr[j*4+1] = v.y * SCALE;
        qr[j*4+2] = v.z * SCALE; qr[j*4+3] = v.w * SCALE;
    }

    float m[4], l[4];
    f32x4 acc[4];
#pragma unroll
    for (int j = 0; j < 4; ++j) {
        m[j] = -1e30f; l[j] = 0.f;
        acc[j] = (f32x4){0.f, 0.f, 0.f, 0.f};
    }

    f32x4 a[4], b[4];
    {
        const float* ksrc = kc + (size_t)r0 * EDIM;
        const float* vsrc = vc + (size_t)r0 * EDIM;
#pragma unroll
        for (int j = 0; j < 4; ++j) a[j] = ntload4(ksrc + j * 1024 + c0);
#pragma unroll
        for (int j = 0; j < 4; ++j) b[j] = ntload4(vsrc + j * 1024 + c0);
    }

    for (int i = 0; i < nr; ++i) {
        int row = r0 + i;
        f32x4 a2[4], b2[4];
        if (i + 1 < nr) {
            const float* ksrc = kc + (size_t)(row + 1) * EDIM;
            const float* vsrc = vc + (size_t)(row + 1) * EDIM;
#pragma unroll
            for (int j = 0; j < 4; ++j) a2[j] = ntload4(ksrc + j * 1024 + c0);
#pragma unroll
            for (int j = 0; j < 4; ++j) b2[j] = ntload4(vsrc + j * 1024 + c0);
        }
        {
            float* kd = knew + (size_t)row * EDIM;
            float* vd = vnew + (size_t)row * EDIM;
#pragma unroll
            for (int j = 0; j < 4; ++j) ntstore4(kd + j * 1024 + c0, a[j]);
#pragma unroll
            for (int j = 0; j < 4; ++j) ntstore4(vd + j * 1024 + c0, b[j]);
        }
        float pd[4];
#pragma unroll
        for (int j = 0; j < 4; ++j)
            pd[j] = a[j].x * qr[j*4+0] + a[j].y * qr[j*4+1] +
                    a[j].z * qr[j*4+2] + a[j].w * qr[j*4+3];
#pragma unroll
        for (int msk = 1; msk <= 16; msk <<= 1) {
#pragma unroll
            for (int j = 0; j < 4; ++j) pd[j] += __shfl_xor(pd[j], msk);
        }
#pragma unroll
        for (int j = 0; j < 4; ++j) {
            float mn = fmaxf(m[j], pd[j]);
            float r  = __expf(m[j] - mn);
            float p  = __expf(pd[j] - mn);
            l[j] = l[j] * r + p;
            acc[j] = acc[j] * r + p * b[j];
            m[j] = mn;
        }
#pragma unroll
        for (int j = 0; j < 4; ++j) { a[j] = a2[j]; b[j] = b2[j]; }
    }

    int lane32 = t & 31;
    if (lane32 == 0) {
#pragma unroll
        for (int j = 0; j < 4; ++j) {
            int head = j * 8 + g;
            pm[(size_t)head * NSPLIT + s] = m[j];
            pl[(size_t)head * NSPLIT + s] = l[j];
        }
    }
#pragma unroll
    for (int j = 0; j < 4; ++j) {
        int head = j * 8 + g;
        *(f32x4*)(po + ((size_t)head * NSPLIT + s) * DHEAD + lane32 * 4) = acc[j];
    }
}

// ---------------------------------------------------------------------------
// Kernel 3: combine stage 1.  grid (NHEAD, NGRP), 256 thr = 8 subgroups
// of 32 lanes; lane owns f32x4 of head dim; subgroup strides splits.
// ---------------------------------------------------------------------------
__global__ __launch_bounds__(256) void combine1_kernel(
    const float* __restrict__ pm, const float* __restrict__ pl,
    const float* __restrict__ po,
    float* __restrict__ gm, float* __restrict__ gl, float* __restrict__ go)
{
    int h   = blockIdx.x;
    int grp = blockIdx.y;
    int t   = threadIdx.x;
    int sg  = t >> 5;
    int ln  = t & 31;
    int s0  = grp * SPG;

    __shared__ float sm[SPG], sw[SPG];
    __shared__ f32x4 red[8][32];
    __shared__ float redl[8];

    if (t < SPG) {
        sm[t] = pm[(size_t)h * NSPLIT + s0 + t];
        sw[t] = pl[(size_t)h * NSPLIT + s0 + t];
    }
    __syncthreads();

    float M = -1e30f;
#pragma unroll 8
    for (int i = 0; i < SPG; ++i) M = fmaxf(M, sm[i]);

    f32x4 o4 = (f32x4){0.f, 0.f, 0.f, 0.f};
    float L = 0.f;
    for (int i = sg; i < SPG; i += 8) {
        float w = __expf(sm[i] - M);
        o4 += w * ld4(po + ((size_t)h * NSPLIT + s0 + i) * DHEAD + ln * 4);
        L += w * sw[i];
    }
    red[sg][ln] = o4;
    if (ln == 0) redl[sg] = L;
    __syncthreads();
    if (sg == 0) {
        f32x4 oo = red[0][ln];
#pragma unroll
        for (int k = 1; k < 8; ++k) oo += red[k][ln];
        *(f32x4*)(go + ((size_t)h * NGRP + grp) * DHEAD + ln * 4) = oo;
        if (ln == 0) {
            float LL = redl[0];
#pragma unroll
            for (int k = 1; k < 8; ++k) LL += redl[k];
            gm[h * NGRP + grp] = M;
            gl[h * NGRP + grp] = LL;
        }
    }
}

// ---------------------------------------------------------------------------
// Kernel 4: combine stage 2 + row-8191 contribution.  grid NHEAD, 128 thr.
// Computes s = q_h . k_new[8191]_h * SCALE in-block, merges with NGRP groups.
// ---------------------------------------------------------------------------
__global__ __launch_bounds__(128) void combine2_kernel(
    const float* __restrict__ gm, const float* __restrict__ gl,
    const float* __restrict__ go, const float* __restrict__ q_f,
    const float* __restrict__ out_ro, float* __restrict__ attn_f)
{
    int h = blockIdx.x;
    int d = threadIdx.x;

    const float* krow = out_ro + (size_t)EDIM * (1 + LCACHE) + h * DHEAD;
    const float* vrow = out_ro + (size_t)EDIM * (1 + LTOT + LCACHE) + h * DHEAD;

    // 128-wide dot product for the new row's score
    __shared__ float cross[2];
    float part = q_f[h * DHEAD + d] * krow[d];
#pragma unroll
    for (int msk = 32; msk; msk >>= 1) part += __shfl_xor(part, msk);
    if ((d & 63) == 0) cross[d >> 6] = part;
    __syncthreads();
    float s_new = (cross[0] + cross[1]) * SCALE;

    float M = s_new;
#pragma unroll
    for (int g = 0; g < NGRP; ++g) M = fmaxf(M, gm[h * NGRP + g]);
    float o = 0.f, L = 0.f;
#pragma unroll
    for (int g = 0; g < NGRP; ++g) {
        float w = __expf(gm[h * NGRP + g] - M);
        o += w * go[((size_t)h * NGRP + g) * DHEAD + d];
        L += w * gl[h * NGRP + g];
    }
    float wn = __expf(s_new - M);
    o += wn * vrow[d];
    L += wn;
    attn_f[h * DHEAD + d] = o / L;
}

// ---------------------------------------------------------------------------
// Kernel 5: output projection. One wave per row, 4 rows/block, grid 1024.
// ---------------------------------------------------------------------------
__global__ __launch_bounds__(256) void proj_kernel(
    const float* __restrict__ attn_f, const float* __restrict__ Wq,
    const float* __restrict__ bq, float* __restrict__ out)
{
    int row  = blockIdx.x * 4 + (threadIdx.x >> 6);
    int lane = threadIdx.x & 63;
    const float* wr = Wq + (size_t)row * EDIM;

    float sum = 0.f;
#pragma unroll
    for (int i = 0; i < 16; ++i) {
        int c = (i * 64 + lane) * 4;
        f32x4 w = ld4(wr + c);
        f32x4 a = ld4(attn_f + c);
        sum += w.x * a.x + w.y * a.y + w.z * a.z + w.w * a.w;
    }
#pragma unroll
    for (int m = 32; m; m >>= 1) sum += __shfl_xor(sum, m);
    if (lane == 0)
        out[row] = sum + bq[row];
}

// ---------------------------------------------------------------------------
extern "C" void kernel_launch(void* const* d_in, const int* in_sizes, int n_in,
                              void* d_out, int out_size, void* d_ws, size_t ws_size,
                              hipStream_t stream)
{
    const float* seq = (const float*)d_in[0];
    const float* kc  = (const float*)d_in[1];
    const float* vc  = (const float*)d_in[2];
    const float* Wq  = (const float*)d_in[3];
    const float* bq  = (const float*)d_in[4];
    const float* Wk  = (const float*)d_in[5];
    const float* bk  = (const float*)d_in[6];
    const float* Wv  = (const float*)d_in[7];
    const float* bv  = (const float*)d_in[8];
    float* out = (float*)d_out;

    float* wsf    = (float*)d_ws;
    float* q_f    = wsf;                        // 4096
    float* attn_f = wsf + 4096;                 // 4096
    float* pm     = wsf + 8192;                 // 32*1024
    float* pl     = pm + NHEAD * NSPLIT;        // 32*1024
    float* gm     = pl + NHEAD * NSPLIT;        // 32*8
    float* gl     = gm + NHEAD * NGRP;          // 32*8
    float* go     = gl + NHEAD * NGRP;          // 32*8*128
    float* po     = go + NHEAD * NGRP * DHEAD;  // 32*1024*128

    hipLaunchKernelGGL(qgemv_kernel, dim3(1024), dim3(256), 0, stream,
                       seq, Wq, bq, q_f);
    hipLaunchKernelGGL(mega_kernel, dim3(NSPLIT + 2048), dim3(256), 0, stream,
                       kc, vc, q_f, seq, Wk, bk, Wv, bv, out, pm, pl, po);
    hipLaunchKernelGGL(combine1_kernel, dim3(NHEAD, NGRP), dim3(256), 0, stream,
                       pm, pl, po, gm, gl, go);
    hipLaunchKernelGGL(combine2_kernel, dim3(NHEAD), dim3(128), 0, stream,
                       gm, gl, go, q_f, out, attn_f);
    hipLaunchKernelGGL(proj_kernel, dim3(1024), dim3(256), 0, stream,
                       attn_f, Wq, bq, out);
}